// Round 9
// baseline (168.395 us; speedup 1.0000x reference)
//
#include <hip/hip_runtime.h>
#include <hip/hip_bf16.h>

// GPT2 attention, B=2 S=2048 E=1024 H=16 hd=64.
// prep (cast X + transpose both weights); MFMA GEMM qkv r19: r16 k-loop
// (128x128, 8 waves x 32x64, dbuf global_load_lds, 1 barrier/k-step, Q
// pre-scaled 0.125*log2e) + NEW vectorized epilogue: Q/K packed through
// XOR-swizzled LDS then 16B stores (was 32 scalar 2B stores/thread).
// flash attention r19: attn6 core (32x32x16, 2 k-parity groups, swapped QK^T,
// exp2 softmax, permlane frag build, gload_lds dbuf, 1 barrier/pair) + NEW
// LDS-packed 16B output stores.  proj GEMM r19: r16 k-loop + LDS-packed
// float4 stores (2 row-passes).  4 launches.

typedef __attribute__((ext_vector_type(4))) float f32x4;
typedef __attribute__((ext_vector_type(16))) float f32x16;
typedef __attribute__((ext_vector_type(8))) short short8;
typedef __attribute__((ext_vector_type(2))) unsigned int uint2v;

#define AS1 __attribute__((address_space(1)))
#define AS3 __attribute__((address_space(3)))

__device__ __forceinline__ void load_lds16(const void* g, void* l) {
    __builtin_amdgcn_global_load_lds((const AS1 void*)g, (AS3 void*)l, 16, 0, 0);
}

__device__ __forceinline__ unsigned short f2bf(float f) {       // RNE
    union { float f; unsigned int u; } v; v.f = f;
    unsigned int r = v.u + 0x7FFFu + ((v.u >> 16) & 1u);
    return (unsigned short)(r >> 16);
}

__device__ __forceinline__ int cvt_pk_bf16(float lo, float hi) {  // [bf16(lo) | bf16(hi)<<16]
    int r;
    asm("v_cvt_pk_bf16_f32 %0, %1, %2" : "=v"(r) : "v"(lo), "v"(hi));
    return r;
}

__device__ __forceinline__ float fexp2(float x) {               // 2^x
    float r;
    asm("v_exp_f32 %0, %1" : "=v"(r) : "v"(x));
    return r;
}

// ---------------------------------------------------------------- prep: cast + weight transposes
__device__ __forceinline__ void transpose_tile(
    const float* __restrict__ W, unsigned short* __restrict__ Wt,
    int K, int N, int bx, int by, int t) {
    __shared__ float tile[32][33];
    int k0 = by * 32, n0 = bx * 32;
    int r = t >> 3, c = (t & 7) * 4;
    float4 v = *(const float4*)&W[(size_t)(k0 + r) * N + n0 + c];
    tile[r][c] = v.x; tile[r][c + 1] = v.y; tile[r][c + 2] = v.z; tile[r][c + 3] = v.w;
    __syncthreads();
    int n = t >> 3; int kk = (t & 7) * 4;
    ushort4 o;
    o.x = f2bf(tile[kk + 0][n]);
    o.y = f2bf(tile[kk + 1][n]);
    o.z = f2bf(tile[kk + 2][n]);
    o.w = f2bf(tile[kk + 3][n]);
    *(ushort4*)&Wt[(size_t)(n0 + n) * K + k0 + kk] = o;
}

// grid 8192: [0,4096) cast X; [4096,7168) transpose W_attn; [7168,8192) transpose W_proj
__global__ __launch_bounds__(256) void prep(
    const float* __restrict__ hs, unsigned short* __restrict__ Xb,
    const float* __restrict__ W_attn, unsigned short* __restrict__ WaT,
    const float* __restrict__ W_proj, unsigned short* __restrict__ WpT) {
    int bid = blockIdx.x, t = threadIdx.x;
    if (bid < 4096) {
        int i = (bid * 256 + t) * 4;
        float4 v = *(const float4*)(hs + i);
        ushort4 o;
        o.x = f2bf(v.x); o.y = f2bf(v.y); o.z = f2bf(v.z); o.w = f2bf(v.w);
        *(ushort4*)(Xb + i) = o;
    } else if (bid < 7168) {
        int r = bid - 4096;                       // dims (96, 32)
        transpose_tile(W_attn, WaT, 1024, 3072, r % 96, r / 96, t);
    } else {
        int r = bid - 7168;                       // dims (32, 32)
        transpose_tile(W_proj, WpT, 1024, 1024, r % 32, r / 32, t);
    }
}

// ---------------------------------------------------------------- qkv GEMM r19 (128x128, 8 waves, dbuf, vec epilogue)
__global__ __launch_bounds__(512, 6) void gemm_qkv(
    const unsigned short* __restrict__ A,
    const unsigned short* __restrict__ Bt,
    const float* __restrict__ bias,
    unsigned short* __restrict__ qk, unsigned short* __restrict__ Vt,
    int M, int N, int K) {
    __shared__ unsigned short Sh[2][8192];       // [buf][As 4096 | Bs 4096]; epilogue overlays
    unsigned short* Qb = &Sh[0][0];              // [128][64] bf16, swizzled
    unsigned short* Tb = &Sh[0][0];              // [64][136] V-transpose
    const int t = threadIdx.x, wave = t >> 6, lane = t & 63;
    const int l15 = lane & 15, quad = lane >> 4;
    const int m0 = blockIdx.y * 128, n0 = blockIdx.x * 128;
    const int sw = wave & 3;
    const bool isB = wave >= 4;
    const int srow = sw * 32 + (lane >> 2);
    const int sch = (lane & 3) * 8;
    const unsigned short* G0 = isB ? (Bt + (size_t)(n0 + srow) * K + sch)
                                   : (A + (size_t)(m0 + srow) * K + sch);
    const int stOff = (isB ? 4096 : 0) + sw * 1024;
    const int wr = wave >> 1, wc = wave & 1;     // 4x2 wave grid, 32x64 each
    f32x4 acc[2][4] = {};
    const int NSTEP = K / 32;                    // 32
    load_lds16(G0, &Sh[0][stOff]);
    load_lds16(G0 + (size_t)16 * K, &Sh[0][stOff + 512]);
    for (int kt = 0; kt < NSTEP; ++kt) {
        const int cur = kt & 1;
        const unsigned short* As = &Sh[cur][0];
        const unsigned short* Bs = &Sh[cur][4096];
        __syncthreads();                         // buf[cur] ready; buf[cur^1] reads done
        if (kt + 1 < NSTEP) {
            const int k1 = (kt + 1) * 32;
            load_lds16(G0 + k1, &Sh[cur ^ 1][stOff]);
            load_lds16(G0 + k1 + (size_t)16 * K, &Sh[cur ^ 1][stOff + 512]);
        }
        short8 af[2], bf[4];
#pragma unroll
        for (int i = 0; i < 2; ++i)
            af[i] = *(const short8*)&As[(wr * 32 + i * 16 + l15) * 32 + quad * 8];
#pragma unroll
        for (int i = 0; i < 4; ++i)
            bf[i] = *(const short8*)&Bs[(wc * 64 + i * 16 + l15) * 32 + quad * 8];
        __builtin_amdgcn_s_setprio(1);
#pragma unroll
        for (int mt = 0; mt < 2; ++mt)
#pragma unroll
            for (int nt = 0; nt < 4; ++nt)
                acc[mt][nt] = __builtin_amdgcn_mfma_f32_16x16x32_bf16(af[mt], bf[nt], acc[mt][nt], 0, 0, 0);
        __builtin_amdgcn_s_setprio(0);
    }
    __syncthreads();                             // all k-loop LDS reads done before overlays
    // epilogue: per 64-col half, uniformly Q, K, or V (n0%192 in {0,64,128}).
#pragma unroll
    for (int hv = 0; hv < 2; ++hv) {
        const int colbase = n0 + hv * 64;
        const int h = colbase / 192;
        const int j0 = colbase - h * 192;        // 0 (Q) | 64 (K) | 128 (V)
        const bool isV = (j0 == 128);
        if (wc == hv) {
            if (!isV) {
                // fold 1/sqrt(hd) AND log2(e) into Q so attn softmax is raw exp2
                const float sc = (j0 == 0) ? 0.18033688011f : 1.0f;
#pragma unroll
                for (int mt = 0; mt < 2; ++mt) {
                    int rbase = wr * 32 + mt * 16 + quad * 4;
#pragma unroll
                    for (int nt = 0; nt < 4; ++nt) {
                        int col = nt * 16 + l15;
                        float bv = bias[colbase + col];
#pragma unroll
                        for (int r = 0; r < 4; ++r) {
                            int row = rbase + r;
                            Qb[row * 64 + (col ^ ((row & 7) << 3))] =
                                f2bf((acc[mt][nt][r] + bv) * sc);
                        }
                    }
                }
            } else {
#pragma unroll
                for (int mt = 0; mt < 2; ++mt) {
                    int s_local = wr * 32 + mt * 16 + quad * 4;
#pragma unroll
                    for (int nt = 0; nt < 4; ++nt) {
                        int d = nt * 16 + l15;
                        float bv = bias[colbase + d];
                        ushort4 pk;
                        pk.x = f2bf(acc[mt][nt][0] + bv);
                        pk.y = f2bf(acc[mt][nt][1] + bv);
                        pk.z = f2bf(acc[mt][nt][2] + bv);
                        pk.w = f2bf(acc[mt][nt][3] + bv);
                        *(ushort4*)&Tb[d * 136 + s_local] = pk;
                    }
                }
            }
        }
        __syncthreads();
        if (!isV) {                              // 1024 16B chunks, 2/thread
            const int qkcol0 = h * 128 + j0;
#pragma unroll
            for (int cc = 0; cc < 2; ++cc) {
                int c = cc * 512 + t;
                int row = c >> 3, ch = c & 7;
                *(uint4*)&qk[(size_t)(m0 + row) * 2048 + qkcol0 + ch * 8] =
                    *(const uint4*)&Qb[row * 64 + ((ch ^ (row & 7)) * 8)];
            }
        } else {
            int b = m0 >> 11;
            unsigned short* vbase = Vt + ((size_t)(b * 16 + h) * 64) * 2048 + (m0 & 2047);
            int drow = t >> 4, ch = (t & 15) * 8;
#pragma unroll
            for (int rr = 0; rr < 2; ++rr) {
                int d = rr * 32 + drow;
                *(uint4*)(vbase + (size_t)d * 2048 + ch) = *(const uint4*)&Tb[d * 136 + ch];
            }
        }
        __syncthreads();                         // region reuse safe before next half
    }
}

// ---------------------------------------------------------------- proj GEMM r19, 128x64, 8 waves, dbuf, vec epilogue
__global__ __launch_bounds__(512, 4) void gemm_proj(
    const unsigned short* __restrict__ A,
    const unsigned short* __restrict__ Bt,
    const float* __restrict__ bias,
    float* __restrict__ C, int M, int N, int K) {
    __shared__ unsigned short Sh[2][6144];       // [buf][As 4096 | Bs 2048]; Fb overlays
    const int t = threadIdx.x, wave = t >> 6, lane = t & 63;
    const int l15 = lane & 15, quad = lane >> 4;
    const int m0 = blockIdx.y * 128, n0 = blockIdx.x * 64;
    const int sw = wave & 3;
    const bool isB = wave >= 4;
    const int srow = isB ? (sw * 16 + (lane >> 2)) : (sw * 32 + (lane >> 2));
    const int sch = (lane & 3) * 8;
    const unsigned short* G0 = isB ? (Bt + (size_t)(n0 + srow) * K + sch)
                                   : (A + (size_t)(m0 + srow) * K + sch);
    const int stOff = isB ? (4096 + sw * 512) : (sw * 1024);
    const int wr = wave >> 1, wc = wave & 1;     // 4x2 wave grid, 32x32 each
    f32x4 acc[2][2] = {};
    const int NSTEP = K / 32;
    load_lds16(G0, &Sh[0][stOff]);
    if (!isB) load_lds16(G0 + (size_t)16 * K, &Sh[0][stOff + 512]);
    for (int kt = 0; kt < NSTEP; ++kt) {
        const int cur = kt & 1;
        const unsigned short* As = &Sh[cur][0];
        const unsigned short* Bs = &Sh[cur][4096];
        __syncthreads();
        if (kt + 1 < NSTEP) {
            const int k1 = (kt + 1) * 32;
            load_lds16(G0 + k1, &Sh[cur ^ 1][stOff]);
            if (!isB) load_lds16(G0 + k1 + (size_t)16 * K, &Sh[cur ^ 1][stOff + 512]);
        }
        short8 af[2], bf[2];
#pragma unroll
        for (int i = 0; i < 2; ++i)
            af[i] = *(const short8*)&As[(wr * 32 + i * 16 + l15) * 32 + quad * 8];
#pragma unroll
        for (int i = 0; i < 2; ++i)
            bf[i] = *(const short8*)&Bs[(wc * 32 + i * 16 + l15) * 32 + quad * 8];
        __builtin_amdgcn_s_setprio(1);
#pragma unroll
        for (int mt = 0; mt < 2; ++mt)
#pragma unroll
            for (int nt = 0; nt < 2; ++nt)
                acc[mt][nt] = __builtin_amdgcn_mfma_f32_16x16x32_bf16(af[mt], bf[nt], acc[mt][nt], 0, 0, 0);
        __builtin_amdgcn_s_setprio(0);
    }
    // epilogue: 2 row-passes through Fb[64][64] f32 (16KB), float4 stores
    float* Fb = (float*)Sh;
#pragma unroll
    for (int pass = 0; pass < 2; ++pass) {
        __syncthreads();
        if ((wr >> 1) == pass) {
#pragma unroll
            for (int mt = 0; mt < 2; ++mt) {
                int rbase = (wr & 1) * 32 + mt * 16 + quad * 4;
#pragma unroll
                for (int nt = 0; nt < 2; ++nt) {
                    int col = wc * 32 + nt * 16 + l15;
                    float bv = bias[n0 + col];
#pragma unroll
                    for (int r = 0; r < 4; ++r) {
                        int row = rbase + r;
                        Fb[row * 64 + (col ^ ((row & 7) << 2))] = acc[mt][nt][r] + bv;
                    }
                }
            }
        }
        __syncthreads();
#pragma unroll
        for (int cc = 0; cc < 2; ++cc) {
            int c = cc * 512 + t;
            int row = c >> 4, ch = c & 15;
            *(float4*)&C[(size_t)(m0 + pass * 64 + row) * N + n0 + ch * 4] =
                *(const float4*)&Fb[row * 64 + ((ch ^ (row & 7)) << 2)];
        }
    }
}

// ---------------------------------------------------------------- flash attention r19
// attn6 core (unchanged): 32x32x16 swapped QK^T, 2 k-parity groups x 4
// q-strips, gload_lds dbuf (linear dest + inverse-swizzled source), one
// barrier per pair-step.  NEW: output packed through LDS, 16B stores.
__global__ __launch_bounds__(512, 4) void attn7(
    const unsigned short* __restrict__ qk,   // [B*S][2048], head h: [h*128+q | +64 k]
    const unsigned short* __restrict__ Vt,   // [B*H][64][2048]
    unsigned short* __restrict__ out) {      // [B*S][1024]
    const int S = 2048;
    __shared__ unsigned short Sh[2][16384];      // [buf][KE|KO|VE|VO], each 64x64 swizzled
    const int t = threadIdx.x, wave = t >> 6, lane = t & 63;
    const int l31 = lane & 31, half = lane >> 5;
    const int g = wave >> 2, gw = wave & 3;      // k-parity group, wave-in-group
    const int bid = blockIdx.x;
    const int qt = (bid < 256) ? (15 - (bid >> 5)) : ((bid - 256) >> 5);
    const int bh = bid & 31;
    const int b = bh >> 4, h = bh & 15;
    const unsigned short* qkb = qk + (size_t)b * S * 2048 + h * 128;
    const unsigned short* vtb = Vt + (size_t)bh * 64 * 2048;

    const int q0 = qt * 128 + gw * 32;           // this wave's 32 q-rows
    short8 qf[4];                                // Q[q=l31][d = km*16 + half*8 + j]
#pragma unroll
    for (int km = 0; km < 4; ++km)
        qf[km] = *(const short8*)(qkb + (size_t)(q0 + l31) * 2048 + km * 16 + half * 8);

    f32x16 o[2] = {};
    float lrun = 0.f;

    const int srow = t >> 3, c8 = t & 7;
    const int gsw = ((c8 ^ (srow & 7)) * 8);     // shorts offset within 64-col window
    const int ldst = wave * 512;                 // wave-uniform dest (shorts) per sub-tile
    const unsigned short* kSrc = qkb + (size_t)srow * 2048 + 64 + gsw;
    const unsigned short* vSrc = vtb + (size_t)srow * 2048 + gsw;
    const int KTP = qt + 1;                      // pairs of k-tiles

    load_lds16(kSrc, &Sh[0][ldst]);
    load_lds16(kSrc + (size_t)64 * 2048, &Sh[0][4096 + ldst]);
    load_lds16(vSrc, &Sh[0][8192 + ldst]);
    load_lds16(vSrc + 64, &Sh[0][12288 + ldst]);

    const int qmax = q0 + 31;
    const int ksw = l31 & 7;
    int chs[4];                                  // per-km swizzled chunk offsets (shorts)
#pragma unroll
    for (int km = 0; km < 4; ++km)
        chs[km] = ((km * 2 + half) ^ ksw) * 8;
    const int krow = l31 * 64;
    const int gOff = g ? 4096 : 0;

    for (int p = 0; p < KTP; ++p) {
        const int cur = p & 1;
        __syncthreads();                         // pair p staged; buf[cur^1] reads (p-1) done
        if (p + 1 < KTP) {
            const int k2 = (2 * p + 2) * 64;
            unsigned short* nb = &Sh[cur ^ 1][0];
            load_lds16(kSrc + (size_t)k2 * 2048, nb + ldst);
            load_lds16(kSrc + (size_t)(k2 + 64) * 2048, nb + 4096 + ldst);
            load_lds16(vSrc + k2, nb + 8192 + ldst);
            load_lds16(vSrc + k2 + 64, nb + 12288 + ldst);
        }
        const int kb = (2 * p + g) * 64;
        if (kb > qmax) continue;                 // fully masked for this wave

        const unsigned short* Ksg = &Sh[cur][gOff];
        const unsigned short* Vsg = &Sh[cur][8192 + gOff];

        // ---- QK^T (swapped, 32x32x16): 2 k-subtiles x 4 d-windows
        f32x16 s[2] = {};
        __builtin_amdgcn_s_setprio(1);
#pragma unroll
        for (int nt = 0; nt < 2; ++nt)
#pragma unroll
            for (int km = 0; km < 4; ++km) {
                short8 kf = *(const short8*)&Ksg[nt * 2048 + krow + chs[km]];
                s[nt] = __builtin_amdgcn_mfma_f32_32x32x16_bf16(kf, qf[km], s[nt], 0, 0, 0);
            }
        __builtin_amdgcn_s_setprio(0);

        // ---- causal mask (diag region only); Q pre-scaled so s is log2-logit
        if (kb + 63 > q0) {
#pragma unroll
            for (int nt = 0; nt < 2; ++nt)
#pragma unroll
                for (int r = 0; r < 16; ++r) {
                    int kg = kb + nt * 32 + (r & 3) + 8 * (r >> 2) + 4 * half;
                    if (kg > q0 + l31) s[nt][r] = -1e30f;
                }
        }

        // ---- softmax (no-max, exp2) + pack, fully in registers
        int gd[2][4][2];                         // [nt][reg-group][dword]
        float a0 = 0.f;
#pragma unroll
        for (int nt = 0; nt < 2; ++nt)
#pragma unroll
            for (int gg = 0; gg < 4; ++gg) {
                float e0 = fexp2(s[nt][4 * gg + 0]);
                float e1 = fexp2(s[nt][4 * gg + 1]);
                float e2 = fexp2(s[nt][4 * gg + 2]);
                float e3 = fexp2(s[nt][4 * gg + 3]);
                a0 += (e0 + e1) + (e2 + e3);
                gd[nt][gg][0] = cvt_pk_bf16(e0, e1);
                gd[nt][gg][1] = cvt_pk_bf16(e2, e3);
            }
        lrun += a0;

        // ---- PV A-frags: 2 permlane32_swap per k-window
        short8 paf[4];
#pragma unroll
        for (int km = 0; km < 4; ++km) {
            const int nt = km >> 1, m = km & 1;
            uint2v w0 = __builtin_amdgcn_permlane32_swap(
                (unsigned)gd[nt][2 * m][0], (unsigned)gd[nt][2 * m + 1][0], false, false);
            uint2v w1 = __builtin_amdgcn_permlane32_swap(
                (unsigned)gd[nt][2 * m][1], (unsigned)gd[nt][2 * m + 1][1], false, false);
            int4 v = {(int)w0[0], (int)w1[0], (int)w0[1], (int)w1[1]};
            paf[km] = __builtin_bit_cast(short8, v);
        }

        // ---- PV (32x32x16): 2 d-subtiles x 4 k-windows
        __builtin_amdgcn_s_setprio(1);
#pragma unroll
        for (int nt2 = 0; nt2 < 2; ++nt2)
#pragma unroll
            for (int km = 0; km < 4; ++km) {
                short8 vf = *(const short8*)&Vsg[nt2 * 2048 + krow + chs[km]];
                o[nt2] = __builtin_amdgcn_mfma_f32_32x32x16_bf16(paf[km], vf, o[nt2], 0, 0, 0);
            }
        __builtin_amdgcn_s_setprio(0);
    }
    __syncthreads();                             // all LDS reads done before epilogue overlay

    // ---- epilogue: additive combine (no-max softmax), LDS pack, 16B stores
    float* Lf = (float*)&Sh[0][0];               // combine staging (<= 17.4KB)
    unsigned short* Pb = &Sh[1][0];              // [128][64] bf16, swizzled (16KB)
    const int cidx = gw * 64 + lane;
    if (g == 1) {
        float* dst = Lf + cidx * 17;
#pragma unroll
        for (int r = 0; r < 16; ++r) dst[r] = o[0][r];
        dst[16] = lrun;
    }
    __syncthreads();
    float lsum = lrun;
    if (g == 0) {
        const float* src = Lf + cidx * 17;
#pragma unroll
        for (int r = 0; r < 16; ++r) o[0][r] += src[r];
        lsum += src[16];
    }
    __syncthreads();
    if (g == 1) {
        float* dst = Lf + cidx * 16;
#pragma unroll
        for (int r = 0; r < 16; ++r) dst[r] = o[1][r];
    }
    __syncthreads();
    if (g == 0) {
        const float* src = Lf + cidx * 16;
#pragma unroll
        for (int r = 0; r < 16; ++r) o[1][r] += src[r];
        float tot = lsum + __shfl_xor(lsum, 32);
#pragma unroll
        for (int r = 0; r < 16; ++r) {
            int ql = (r & 3) + 8 * (r >> 2) + 4 * half;   // output q-row of reg r
            float inv = 1.0f / __shfl(tot, ql);           // sum for q=ql at lane l31==ql
            int row = gw * 32 + ql;
            int sz = (row & 7) << 3;
            Pb[row * 64 + (l31 ^ sz)] = f2bf(o[0][r] * inv);
            Pb[row * 64 + ((32 + l31) ^ sz)] = f2bf(o[1][r] * inv);
        }
    }
    __syncthreads();
    unsigned short* ob = out + (size_t)b * S * 1024 + h * 64;
#pragma unroll
    for (int cc = 0; cc < 2; ++cc) {             // 1024 16B chunks, 2/thread
        int c = cc * 512 + t;
        int row = c >> 3, ch = c & 7;
        *(uint4*)&ob[(size_t)(qt * 128 + row) * 1024 + ch * 8] =
            *(const uint4*)&Pb[row * 64 + ((ch ^ (row & 7)) * 8)];
    }
}

// ----------------------------------------------------------------
extern "C" void kernel_launch(void* const* d_in, const int* in_sizes, int n_in,
                              void* d_out, int out_size, void* d_ws, size_t ws_size,
                              hipStream_t stream) {
    const float* hs     = (const float*)d_in[0];
    const float* W_attn = (const float*)d_in[1];
    const float* b_attn = (const float*)d_in[2];
    const float* W_proj = (const float*)d_in[3];
    const float* b_proj = (const float*)d_in[4];
    float* out = (float*)d_out;

    const int B = 2, S = 2048, E = 1024;
    const int M = B * S;        // 4096
    const int N3 = 3 * E;       // 3072

    unsigned short* Xb  = (unsigned short*)d_ws;          // M*E
    unsigned short* WaT = Xb + (size_t)M * E;             // N3*E
    unsigned short* WpT = WaT + (size_t)N3 * E;           // E*E
    unsigned short* qkb = WpT + (size_t)E * E;            // M*2048
    unsigned short* Vt  = qkb + (size_t)M * 2048;         // M*E
    unsigned short* ao  = Vt + (size_t)M * E;             // M*E

    prep<<<dim3(8192), 256, 0, stream>>>(hs, Xb, W_attn, WaT, W_proj, WpT);

    gemm_qkv<<<dim3(N3 / 128, M / 128), 512, 0, stream>>>(Xb, WaT, b_attn, qkb, Vt, M, N3, E);

    attn7<<<dim3(512), 512, 0, stream>>>(qkb, Vt, ao);

    gemm_proj<<<dim3(E / 64, M / 128), 512, 0, stream>>>(ao, WpT, b_proj, out, M, E, E);
}

// Round 10
// 166.228 us; speedup vs baseline: 1.0130x; 1.0130x over previous
//
#include <hip/hip_runtime.h>
#include <hip/hip_bf16.h>

// GPT2 attention, B=2 S=2048 E=1024 H=16 hd=64.
// prep (cast X + transpose both weights); MFMA GEMM qkv r20: r16 k-loop
// (128x128, 8 waves x 32x64, global_load_lds) upgraded to 3-buffer COUNTED
// vmcnt pipeline: s_waitcnt vmcnt(2) + raw s_barrier per step (no vmcnt(0)
// drain; no sched_barrier / lgkm drain — r18's poison), stage kt+2 each step.
// flash attention r17 verbatim (32x32x16 swapped core, 2 k-parity groups,
// exp2 softmax, permlane frag build, gload_lds dbuf, 1 barrier/pair).
// proj GEMM r20: r16 + same counted-vmcnt 3-buffer pipeline. 4 launches.

typedef __attribute__((ext_vector_type(4))) float f32x4;
typedef __attribute__((ext_vector_type(16))) float f32x16;
typedef __attribute__((ext_vector_type(8))) short short8;
typedef __attribute__((ext_vector_type(2))) unsigned int uint2v;

#define AS1 __attribute__((address_space(1)))
#define AS3 __attribute__((address_space(3)))

__device__ __forceinline__ void load_lds16(const void* g, void* l) {
    __builtin_amdgcn_global_load_lds((const AS1 void*)g, (AS3 void*)l, 16, 0, 0);
}

__device__ __forceinline__ unsigned short f2bf(float f) {       // RNE
    union { float f; unsigned int u; } v; v.f = f;
    unsigned int r = v.u + 0x7FFFu + ((v.u >> 16) & 1u);
    return (unsigned short)(r >> 16);
}

__device__ __forceinline__ int cvt_pk_bf16(float lo, float hi) {  // [bf16(lo) | bf16(hi)<<16]
    int r;
    asm("v_cvt_pk_bf16_f32 %0, %1, %2" : "=v"(r) : "v"(lo), "v"(hi));
    return r;
}

__device__ __forceinline__ float fexp2(float x) {               // 2^x
    float r;
    asm("v_exp_f32 %0, %1" : "=v"(r) : "v"(x));
    return r;
}

// ---------------------------------------------------------------- prep: cast + weight transposes
__device__ __forceinline__ void transpose_tile(
    const float* __restrict__ W, unsigned short* __restrict__ Wt,
    int K, int N, int bx, int by, int t) {
    __shared__ float tile[32][33];
    int k0 = by * 32, n0 = bx * 32;
    int r = t >> 3, c = (t & 7) * 4;
    float4 v = *(const float4*)&W[(size_t)(k0 + r) * N + n0 + c];
    tile[r][c] = v.x; tile[r][c + 1] = v.y; tile[r][c + 2] = v.z; tile[r][c + 3] = v.w;
    __syncthreads();
    int n = t >> 3; int kk = (t & 7) * 4;
    ushort4 o;
    o.x = f2bf(tile[kk + 0][n]);
    o.y = f2bf(tile[kk + 1][n]);
    o.z = f2bf(tile[kk + 2][n]);
    o.w = f2bf(tile[kk + 3][n]);
    *(ushort4*)&Wt[(size_t)(n0 + n) * K + k0 + kk] = o;
}

// grid 8192: [0,4096) cast X; [4096,7168) transpose W_attn; [7168,8192) transpose W_proj
__global__ __launch_bounds__(256) void prep(
    const float* __restrict__ hs, unsigned short* __restrict__ Xb,
    const float* __restrict__ W_attn, unsigned short* __restrict__ WaT,
    const float* __restrict__ W_proj, unsigned short* __restrict__ WpT) {
    int bid = blockIdx.x, t = threadIdx.x;
    if (bid < 4096) {
        int i = (bid * 256 + t) * 4;
        float4 v = *(const float4*)(hs + i);
        ushort4 o;
        o.x = f2bf(v.x); o.y = f2bf(v.y); o.z = f2bf(v.z); o.w = f2bf(v.w);
        *(ushort4*)(Xb + i) = o;
    } else if (bid < 7168) {
        int r = bid - 4096;                       // dims (96, 32)
        transpose_tile(W_attn, WaT, 1024, 3072, r % 96, r / 96, t);
    } else {
        int r = bid - 7168;                       // dims (32, 32)
        transpose_tile(W_proj, WpT, 1024, 1024, r % 32, r / 32, t);
    }
}

// ---------------------------------------------------------------- qkv GEMM r20 (128x128, 8 waves, 3-buf counted vmcnt)
// C = Xb @ WaT^T + bias; qkv split -> qk (Q scaled 0.125*log2e); V -> Vt via
// LDS transpose.  Per step: s_waitcnt vmcnt(2) (batch kt landed, kt+1 in
// flight) -> s_barrier -> issue batch kt+2 -> compute buf[kt%3].  WAR safe:
// buf (kt+2)%3's last reads (step kt-1) completed before each reader's MFMAs,
// which precede barrier kt in program order.
__global__ __launch_bounds__(512, 6) void gemm_qkv(
    const unsigned short* __restrict__ A,
    const unsigned short* __restrict__ Bt,
    const float* __restrict__ bias,
    unsigned short* __restrict__ qk, unsigned short* __restrict__ Vt,
    int M, int N, int K) {
    __shared__ unsigned short Sh[3][8192];       // 48KB: 3 x (As 4096 | Bs 4096)
    unsigned short* Tb = &Sh[0][0];              // epilogue overlay [64][136]
    const int t = threadIdx.x, wave = t >> 6, lane = t & 63;
    const int l15 = lane & 15, quad = lane >> 4;
    const int m0 = blockIdx.y * 128, n0 = blockIdx.x * 128;
    const int sw = wave & 3;
    const bool isB = wave >= 4;
    const int srow = sw * 32 + (lane >> 2);
    const int sch = (lane & 3) * 8;
    const unsigned short* G0 = isB ? (Bt + (size_t)(n0 + srow) * K + sch)
                                   : (A + (size_t)(m0 + srow) * K + sch);
    const int stOff = (isB ? 4096 : 0) + sw * 1024;
    const int wr = wave >> 1, wc = wave & 1;     // 4x2 wave grid, 32x64 each
    f32x4 acc[2][4] = {};
    const int NSTEP = K / 32;                    // 32
#pragma unroll
    for (int pb = 0; pb < 2; ++pb) {             // prologue: batches 0,1
        const int kk = pb * 32;
        load_lds16(G0 + kk, &Sh[pb][stOff]);
        load_lds16(G0 + kk + (size_t)16 * K, &Sh[pb][stOff + 512]);
    }
    int cur = 0, stg = 2;
    for (int kt = 0; kt < NSTEP; ++kt) {
        if (kt + 1 < NSTEP)
            asm volatile("s_waitcnt vmcnt(2)" ::: "memory");
        else
            asm volatile("s_waitcnt vmcnt(0)" ::: "memory");
        __builtin_amdgcn_s_barrier();
        if (kt + 2 < NSTEP) {
            const int k2 = (kt + 2) * 32;
            load_lds16(G0 + k2, &Sh[stg][stOff]);
            load_lds16(G0 + k2 + (size_t)16 * K, &Sh[stg][stOff + 512]);
        }
        const unsigned short* As = &Sh[cur][0];
        const unsigned short* Bs = &Sh[cur][4096];
        short8 af[2], bf[4];
#pragma unroll
        for (int i = 0; i < 2; ++i)
            af[i] = *(const short8*)&As[(wr * 32 + i * 16 + l15) * 32 + quad * 8];
#pragma unroll
        for (int i = 0; i < 4; ++i)
            bf[i] = *(const short8*)&Bs[(wc * 64 + i * 16 + l15) * 32 + quad * 8];
        __builtin_amdgcn_s_setprio(1);
#pragma unroll
        for (int mt = 0; mt < 2; ++mt)
#pragma unroll
            for (int nt = 0; nt < 4; ++nt)
                acc[mt][nt] = __builtin_amdgcn_mfma_f32_16x16x32_bf16(af[mt], bf[nt], acc[mt][nt], 0, 0, 0);
        __builtin_amdgcn_s_setprio(0);
        cur = (cur == 2) ? 0 : cur + 1;
        stg = (stg == 2) ? 0 : stg + 1;
    }
    __syncthreads();                             // full drain before Tb overlay
    const int rem = n0 % 192;                    // 0: no V; 128: half 0 is V; 64: half 1 is V
#pragma unroll
    for (int mt = 0; mt < 2; ++mt) {
        int mrow = m0 + wr * 32 + mt * 16 + quad * 4;
#pragma unroll
        for (int nt = 0; nt < 4; ++nt) {
            int col = n0 + wc * 64 + nt * 16 + l15;
            float bv = bias[col];
            int h = col / 192;
            int j = col - h * 192;
            if (j < 128) {       // Q or K -> qk buffer (both land at h*128 + j)
                // fold 1/sqrt(hd) AND log2(e) into Q so attn softmax is raw exp2
                float sc = (j < 64) ? 0.18033688011f : 1.0f;
#pragma unroll
                for (int r = 0; r < 4; ++r)
                    qk[(size_t)(mrow + r) * 2048 + h * 128 + j] = f2bf((acc[mt][nt][r] + bv) * sc);
            } else {             // V -> LDS transpose buffer Tb[d][s_local]
                int d = j - 128;
                int s_local = wr * 32 + mt * 16 + quad * 4;
                ushort4 pk;
                pk.x = f2bf(acc[mt][nt][0] + bv);
                pk.y = f2bf(acc[mt][nt][1] + bv);
                pk.z = f2bf(acc[mt][nt][2] + bv);
                pk.w = f2bf(acc[mt][nt][3] + bv);
                *(ushort4*)&Tb[d * 136 + s_local] = pk;
            }
        }
    }
    if (rem != 0) {              // block-uniform: barrier legal
        __syncthreads();
        int vhalf = (rem == 64) ? 1 : 0;
        int h = (n0 + vhalf * 64) / 192;
        int b = m0 >> 11;
        unsigned short* vbase = Vt + ((size_t)(b * 16 + h) * 64) * 2048 + (m0 & 2047);
        int drow = t >> 4, ch = (t & 15) * 8;    // 32 rows/pass x 16 chunks of 16B
#pragma unroll
        for (int rr = 0; rr < 2; ++rr) {
            int d = rr * 32 + drow;
            *(uint4*)(vbase + (size_t)d * 2048 + ch) = *(const uint4*)&Tb[d * 136 + ch];
        }
    }
}

// ---------------------------------------------------------------- proj GEMM r20, 128x64, 8 waves, 3-buf counted vmcnt
__global__ __launch_bounds__(512, 4) void gemm_proj(
    const unsigned short* __restrict__ A,
    const unsigned short* __restrict__ Bt,
    const float* __restrict__ bias,
    float* __restrict__ C, int M, int N, int K) {
    __shared__ unsigned short Sh[3][6144];       // 18KB: 3 x (As 4096 | Bs 2048)
    const int t = threadIdx.x, wave = t >> 6, lane = t & 63;
    const int l15 = lane & 15, quad = lane >> 4;
    const int m0 = blockIdx.y * 128, n0 = blockIdx.x * 64;
    const int sw = wave & 3;
    const bool isB = wave >= 4;
    const int srow = isB ? (sw * 16 + (lane >> 2)) : (sw * 32 + (lane >> 2));
    const int sch = (lane & 3) * 8;
    const unsigned short* G0 = isB ? (Bt + (size_t)(n0 + srow) * K + sch)
                                   : (A + (size_t)(m0 + srow) * K + sch);
    const int stOff = isB ? (4096 + sw * 512) : (sw * 1024);
    const int wr = wave >> 1, wc = wave & 1;     // 4x2 wave grid, 32x32 each
    f32x4 acc[2][2] = {};
    const int NSTEP = K / 32;
#pragma unroll
    for (int pb = 0; pb < 2; ++pb) {             // prologue: batches 0,1
        const int kk = pb * 32;
        load_lds16(G0 + kk, &Sh[pb][stOff]);
        if (!isB) load_lds16(G0 + kk + (size_t)16 * K, &Sh[pb][stOff + 512]);
    }
    int cur = 0, stg = 2;
    for (int kt = 0; kt < NSTEP; ++kt) {
        if (kt + 1 < NSTEP) {
            if (!isB) asm volatile("s_waitcnt vmcnt(2)" ::: "memory");
            else      asm volatile("s_waitcnt vmcnt(1)" ::: "memory");
        } else {
            asm volatile("s_waitcnt vmcnt(0)" ::: "memory");
        }
        __builtin_amdgcn_s_barrier();
        if (kt + 2 < NSTEP) {
            const int k2 = (kt + 2) * 32;
            load_lds16(G0 + k2, &Sh[stg][stOff]);
            if (!isB) load_lds16(G0 + k2 + (size_t)16 * K, &Sh[stg][stOff + 512]);
        }
        const unsigned short* As = &Sh[cur][0];
        const unsigned short* Bs = &Sh[cur][4096];
        short8 af[2], bf[2];
#pragma unroll
        for (int i = 0; i < 2; ++i)
            af[i] = *(const short8*)&As[(wr * 32 + i * 16 + l15) * 32 + quad * 8];
#pragma unroll
        for (int i = 0; i < 2; ++i)
            bf[i] = *(const short8*)&Bs[(wc * 32 + i * 16 + l15) * 32 + quad * 8];
        __builtin_amdgcn_s_setprio(1);
#pragma unroll
        for (int mt = 0; mt < 2; ++mt)
#pragma unroll
            for (int nt = 0; nt < 2; ++nt)
                acc[mt][nt] = __builtin_amdgcn_mfma_f32_16x16x32_bf16(af[mt], bf[nt], acc[mt][nt], 0, 0, 0);
        __builtin_amdgcn_s_setprio(0);
        cur = (cur == 2) ? 0 : cur + 1;
        stg = (stg == 2) ? 0 : stg + 1;
    }
#pragma unroll
    for (int mt = 0; mt < 2; ++mt) {
        int mrow = m0 + wr * 32 + mt * 16 + quad * 4;
#pragma unroll
        for (int nt = 0; nt < 2; ++nt) {
            int col = n0 + wc * 32 + nt * 16 + l15;
            float bv = bias[col];
#pragma unroll
            for (int r = 0; r < 4; ++r)
                C[(size_t)(mrow + r) * N + col] = acc[mt][nt][r] + bv;
        }
    }
}

// ---------------------------------------------------------------- flash attention r17 (verbatim)
// 32x32x16 swapped core.  8 waves = 2 k-parity groups x 4 q-strips of 32 rows.
// Staging via global_load_lds into 64KB double buffer (linear LDS dest +
// inverse-swizzled per-lane global source).  One barrier per pair-step.
__global__ __launch_bounds__(512, 4) void attn6(
    const unsigned short* __restrict__ qk,   // [B*S][2048], head h: [h*128+q | +64 k]
    const unsigned short* __restrict__ Vt,   // [B*H][64][2048]
    unsigned short* __restrict__ out) {      // [B*S][1024]
    const int S = 2048;
    __shared__ unsigned short Sh[2][16384];      // [buf][KE|KO|VE|VO], each 64x64 swizzled
    const int t = threadIdx.x, wave = t >> 6, lane = t & 63;
    const int l31 = lane & 31, half = lane >> 5;
    const int g = wave >> 2, gw = wave & 3;      // k-parity group, wave-in-group
    const int bid = blockIdx.x;
    const int qt = (bid < 256) ? (15 - (bid >> 5)) : ((bid - 256) >> 5);
    const int bh = bid & 31;
    const int b = bh >> 4, h = bh & 15;
    const unsigned short* qkb = qk + (size_t)b * S * 2048 + h * 128;
    const unsigned short* vtb = Vt + (size_t)bh * 64 * 2048;

    const int q0 = qt * 128 + gw * 32;           // this wave's 32 q-rows
    short8 qf[4];                                // Q[q=l31][d = km*16 + half*8 + j]
#pragma unroll
    for (int km = 0; km < 4; ++km)
        qf[km] = *(const short8*)(qkb + (size_t)(q0 + l31) * 2048 + km * 16 + half * 8);

    f32x16 o[2] = {};
    float lrun = 0.f;

    const int srow = t >> 3, c8 = t & 7;
    const int gsw = ((c8 ^ (srow & 7)) * 8);     // shorts offset within 64-col window
    const int ldst = wave * 512;                 // wave-uniform dest (shorts) per sub-tile
    const unsigned short* kSrc = qkb + (size_t)srow * 2048 + 64 + gsw;
    const unsigned short* vSrc = vtb + (size_t)srow * 2048 + gsw;
    const int KTP = qt + 1;                      // pairs of k-tiles

    load_lds16(kSrc, &Sh[0][ldst]);
    load_lds16(kSrc + (size_t)64 * 2048, &Sh[0][4096 + ldst]);
    load_lds16(vSrc, &Sh[0][8192 + ldst]);
    load_lds16(vSrc + 64, &Sh[0][12288 + ldst]);

    const int qmax = q0 + 31;
    const int ksw = l31 & 7;
    int chs[4];                                  // per-km swizzled chunk offsets (shorts)
#pragma unroll
    for (int km = 0; km < 4; ++km)
        chs[km] = ((km * 2 + half) ^ ksw) * 8;
    const int krow = l31 * 64;
    const int gOff = g ? 4096 : 0;

    for (int p = 0; p < KTP; ++p) {
        const int cur = p & 1;
        __syncthreads();                         // pair p staged; buf[cur^1] reads (p-1) done
        if (p + 1 < KTP) {
            const int k2 = (2 * p + 2) * 64;
            unsigned short* nb = &Sh[cur ^ 1][0];
            load_lds16(kSrc + (size_t)k2 * 2048, nb + ldst);
            load_lds16(kSrc + (size_t)(k2 + 64) * 2048, nb + 4096 + ldst);
            load_lds16(vSrc + k2, nb + 8192 + ldst);
            load_lds16(vSrc + k2 + 64, nb + 12288 + ldst);
        }
        const int kb = (2 * p + g) * 64;
        if (kb > qmax) continue;                 // fully masked for this wave

        const unsigned short* Ksg = &Sh[cur][gOff];
        const unsigned short* Vsg = &Sh[cur][8192 + gOff];

        // ---- QK^T (swapped, 32x32x16): 2 k-subtiles x 4 d-windows
        f32x16 s[2] = {};
        __builtin_amdgcn_s_setprio(1);
#pragma unroll
        for (int nt = 0; nt < 2; ++nt)
#pragma unroll
            for (int km = 0; km < 4; ++km) {
                short8 kf = *(const short8*)&Ksg[nt * 2048 + krow + chs[km]];
                s[nt] = __builtin_amdgcn_mfma_f32_32x32x16_bf16(kf, qf[km], s[nt], 0, 0, 0);
            }
        __builtin_amdgcn_s_setprio(0);

        // ---- causal mask (diag region only); Q pre-scaled so s is log2-logit
        if (kb + 63 > q0) {
#pragma unroll
            for (int nt = 0; nt < 2; ++nt)
#pragma unroll
                for (int r = 0; r < 16; ++r) {
                    int kg = kb + nt * 32 + (r & 3) + 8 * (r >> 2) + 4 * half;
                    if (kg > q0 + l31) s[nt][r] = -1e30f;
                }
        }

        // ---- softmax (no-max, exp2) + pack, fully in registers
        int gd[2][4][2];                         // [nt][reg-group][dword]
        float a0 = 0.f;
#pragma unroll
        for (int nt = 0; nt < 2; ++nt)
#pragma unroll
            for (int gg = 0; gg < 4; ++gg) {
                float e0 = fexp2(s[nt][4 * gg + 0]);
                float e1 = fexp2(s[nt][4 * gg + 1]);
                float e2 = fexp2(s[nt][4 * gg + 2]);
                float e3 = fexp2(s[nt][4 * gg + 3]);
                a0 += (e0 + e1) + (e2 + e3);
                gd[nt][gg][0] = cvt_pk_bf16(e0, e1);
                gd[nt][gg][1] = cvt_pk_bf16(e2, e3);
            }
        lrun += a0;

        // ---- PV A-frags: 2 permlane32_swap per k-window
        short8 paf[4];
#pragma unroll
        for (int km = 0; km < 4; ++km) {
            const int nt = km >> 1, m = km & 1;
            uint2v w0 = __builtin_amdgcn_permlane32_swap(
                (unsigned)gd[nt][2 * m][0], (unsigned)gd[nt][2 * m + 1][0], false, false);
            uint2v w1 = __builtin_amdgcn_permlane32_swap(
                (unsigned)gd[nt][2 * m][1], (unsigned)gd[nt][2 * m + 1][1], false, false);
            int4 v = {(int)w0[0], (int)w1[0], (int)w0[1], (int)w1[1]};
            paf[km] = __builtin_bit_cast(short8, v);
        }

        // ---- PV (32x32x16): 2 d-subtiles x 4 k-windows
        __builtin_amdgcn_s_setprio(1);
#pragma unroll
        for (int nt2 = 0; nt2 < 2; ++nt2)
#pragma unroll
            for (int km = 0; km < 4; ++km) {
                short8 vf = *(const short8*)&Vsg[nt2 * 2048 + krow + chs[km]];
                o[nt2] = __builtin_amdgcn_mfma_f32_32x32x16_bf16(paf[km], vf, o[nt2], 0, 0, 0);
            }
        __builtin_amdgcn_s_setprio(0);
    }
    __syncthreads();                             // all LDS reads done before epilogue overlay

    // ---- epilogue: combine group partials additively (no-max softmax), then store
    float* Lf = (float*)&Sh[0][0];
    const int cidx = gw * 64 + lane;
    if (g == 1) {
        float* dst = Lf + cidx * 17;
#pragma unroll
        for (int r = 0; r < 16; ++r) dst[r] = o[0][r];
        dst[16] = lrun;
    }
    __syncthreads();
    float lsum = lrun;
    if (g == 0) {
        const float* src = Lf + cidx * 17;
#pragma unroll
        for (int r = 0; r < 16; ++r) o[0][r] += src[r];
        lsum += src[16];
    }
    __syncthreads();
    if (g == 1) {
        float* dst = Lf + cidx * 16;
#pragma unroll
        for (int r = 0; r < 16; ++r) dst[r] = o[1][r];
    }
    __syncthreads();
    if (g == 0) {
        const float* src = Lf + cidx * 16;
#pragma unroll
        for (int r = 0; r < 16; ++r) o[1][r] += src[r];
        float tot = lsum + __shfl_xor(lsum, 32);
        unsigned short* ob = out + (size_t)b * S * 1024 + h * 64;
#pragma unroll
        for (int r = 0; r < 16; ++r) {
            int ql = (r & 3) + 8 * (r >> 2) + 4 * half;   // output q-row of reg r
            float inv = 1.0f / __shfl(tot, ql);           // sum for q=ql at lane l31==ql
            size_t row = (size_t)(q0 + ql) * 1024;
            ob[row + l31] = f2bf(o[0][r] * inv);
            ob[row + 32 + l31] = f2bf(o[1][r] * inv);
        }
    }
}

// ----------------------------------------------------------------
extern "C" void kernel_launch(void* const* d_in, const int* in_sizes, int n_in,
                              void* d_out, int out_size, void* d_ws, size_t ws_size,
                              hipStream_t stream) {
    const float* hs     = (const float*)d_in[0];
    const float* W_attn = (const float*)d_in[1];
    const float* b_attn = (const float*)d_in[2];
    const float* W_proj = (const float*)d_in[3];
    const float* b_proj = (const float*)d_in[4];
    float* out = (float*)d_out;

    const int B = 2, S = 2048, E = 1024;
    const int M = B * S;        // 4096
    const int N3 = 3 * E;       // 3072

    unsigned short* Xb  = (unsigned short*)d_ws;          // M*E
    unsigned short* WaT = Xb + (size_t)M * E;             // N3*E
    unsigned short* WpT = WaT + (size_t)N3 * E;           // E*E
    unsigned short* qkb = WpT + (size_t)E * E;            // M*2048
    unsigned short* Vt  = qkb + (size_t)M * 2048;         // M*E
    unsigned short* ao  = Vt + (size_t)M * E;             // M*E

    prep<<<dim3(8192), 256, 0, stream>>>(hs, Xb, W_attn, WaT, W_proj, WpT);

    gemm_qkv<<<dim3(N3 / 128, M / 128), 512, 0, stream>>>(Xb, WaT, b_attn, qkb, Vt, M, N3, E);

    attn6<<<dim3(512), 512, 0, stream>>>(qkb, Vt, ao);

    gemm_proj<<<dim3(E / 64, M / 128), 512, 0, stream>>>(ao, WpT, b_proj, out, M, E, E);
}